// Round 1
// baseline (202.140 us; speedup 1.0000x reference)
//
#include <hip/hip_runtime.h>

// Problem constants (SynthSeg-style crop): vol [B=4, D=160, H=192, W=160, C=1] fp32,
// trf [4, 4, 4] fp32. Output same shape as vol, fp32.
constexpr int D = 160, H = 192, W = 160, B = 4;
constexpr int V = D * H * W;           // 4,915,200 = 19200 * 256 exactly

struct DimS { int i0, i1; float w0, w1; };

// Faithful to neuron.utils interpn clipping semantics:
//   clipped = clip(loc, 0, max); l0 = clip(floor(loc),0,max); l1 = clip(l0+1,0,max)
//   weight(corner bit 0 -> index l0) = l1 - clipped ; weight(bit 1 -> l1) = 1 - that
__device__ __forceinline__ DimS prep_dim(float loc, float maxv) {
    float cl = fminf(fmaxf(loc, 0.0f), maxv);
    float f0 = floorf(loc);
    float l0 = fminf(fmaxf(f0, 0.0f), maxv);
    float l1 = fminf(l0 + 1.0f, maxv);
    DimS s;
    s.w0 = l1 - cl;        // d1 in reference
    s.w1 = 1.0f - s.w0;    // d0 in reference
    s.i0 = (int)l0;
    s.i1 = (int)l1;
    return s;
}

__global__ __launch_bounds__(256) void st_affine_kernel(
        const float* __restrict__ vol, const float* __restrict__ trf,
        float* __restrict__ out) {
    const int b   = blockIdx.z;
    const int idx = blockIdx.x * 256 + threadIdx.x;   // exact grid, no tail check

    // idx -> (d, h, w); W, H are compile-time constants -> magic-multiply division
    const int w = idx % W;
    const int t = idx / W;
    const int h = t % H;
    const int d = t / H;

    // Affine rows: wave-uniform (b is uniform per block) -> scalar loads
    const float* __restrict__ A = trf + b * 16;
    const float a00 = A[0], a01 = A[1], a02 = A[2],  a03 = A[3];
    const float a10 = A[4], a11 = A[5], a12 = A[6],  a13 = A[7];
    const float a20 = A[8], a21 = A[9], a22 = A[10], a23 = A[11];

    constexpr float cd = (D - 1) * 0.5f;
    constexpr float ch = (H - 1) * 0.5f;
    constexpr float cw = (W - 1) * 0.5f;

    const float md = (float)d - cd;
    const float mh = (float)h - ch;
    const float mw = (float)w - cw;

    // loc = center + A[:3,:3] @ mesh_c + A[:3,3]
    const float ld = cd + fmaf(a00, md, fmaf(a01, mh, fmaf(a02, mw, a03)));
    const float lh = ch + fmaf(a10, md, fmaf(a11, mh, fmaf(a12, mw, a13)));
    const float lw = cw + fmaf(a20, md, fmaf(a21, mh, fmaf(a22, mw, a23)));

    const DimS sd = prep_dim(ld, (float)(D - 1));
    const DimS sh = prep_dim(lh, (float)(H - 1));
    const DimS sw = prep_dim(lw, (float)(W - 1));

    const float* __restrict__ vb = vol + (size_t)b * V;

    const int r00 = (sd.i0 * H + sh.i0) * W;   // (d0,h0) row base
    const int r01 = (sd.i0 * H + sh.i1) * W;   // (d0,h1)
    const int r10 = (sd.i1 * H + sh.i0) * W;   // (d1,h0)
    const int r11 = (sd.i1 * H + sh.i1) * W;   // (d1,h1)

    const float v000 = vb[r00 + sw.i0];
    const float v001 = vb[r00 + sw.i1];
    const float v010 = vb[r01 + sw.i0];
    const float v011 = vb[r01 + sw.i1];
    const float v100 = vb[r10 + sw.i0];
    const float v101 = vb[r10 + sw.i1];
    const float v110 = vb[r11 + sw.i0];
    const float v111 = vb[r11 + sw.i1];

    const float pd0 = fmaf(sw.w0, v000, sw.w1 * v001);
    const float pd1 = fmaf(sw.w0, v010, sw.w1 * v011);
    const float pd2 = fmaf(sw.w0, v100, sw.w1 * v101);
    const float pd3 = fmaf(sw.w0, v110, sw.w1 * v111);

    const float q0 = fmaf(sh.w0, pd0, sh.w1 * pd1);
    const float q1 = fmaf(sh.w0, pd2, sh.w1 * pd3);

    out[(size_t)b * V + idx] = fmaf(sd.w0, q0, sd.w1 * q1);
}

extern "C" void kernel_launch(void* const* d_in, const int* in_sizes, int n_in,
                              void* d_out, int out_size, void* d_ws, size_t ws_size,
                              hipStream_t stream) {
    const float* vol = (const float*)d_in[0];
    const float* trf = (const float*)d_in[1];
    float* out = (float*)d_out;

    dim3 grid(V / 256, 1, B);
    dim3 block(256, 1, 1);
    st_affine_kernel<<<grid, block, 0, stream>>>(vol, trf, out);
}